// Round 1
// baseline (6622.099 us; speedup 1.0000x reference)
//
#include <hip/hip_runtime.h>
#include <hip/hip_bf16.h>
#include <cstdint>

// Problem constants (Qwen3Omni MoE block)
#define T_TOK 2048   // B*S tokens
#define H_DIM 2048
#define I_DIM 768
#define E_NUM 64
#define K_TOP 8

#define TT 16        // tokens per expert-kernel block
#define HC 128       // H chunk staged in LDS

// ---------------- workspace layout ----------------
// [0)        int   topk_idx[T*K]      65536 B
// [65536)    float topk_w[T*K]        65536 B
// [131072)   int   counts[64]
// [131328)   int   offsets[64]
// [131584)   int   cursor[64]
// [131840)   int   perm_token[T*K]    65536 B
// [197376)   float perm_w[T*K]        65536 B
#define WS_TOPK_IDX 0
#define WS_TOPK_W   65536
#define WS_COUNTS   131072
#define WS_OFFSETS  131328
#define WS_CURSOR   131584
#define WS_PERM_TOK 131840
#define WS_PERM_W   197376

// ---------------- router: logits + softmax + top-8 ----------------
__global__ __launch_bounds__(256) void router_kernel(
    const float* __restrict__ x, const float* __restrict__ wr,
    float* __restrict__ out_logits, int* __restrict__ topk_idx,
    float* __restrict__ topk_w) {
  __shared__ __align__(16) float xs[H_DIM];
  __shared__ float part[4][E_NUM];
  const int t = blockIdx.x;
  const int tid = threadIdx.x;

  // stage x row (2048 f32, coalesced float4)
  const float4* xrow = (const float4*)(x + (size_t)t * H_DIM);
  ((float4*)xs)[tid]       = xrow[tid];
  ((float4*)xs)[tid + 256] = xrow[tid + 256];
  __syncthreads();

  const int e = tid & 63;      // expert
  const int q = tid >> 6;      // H quarter
  float sum = 0.f;
  const int h0 = q * (H_DIM / 4);
  for (int h = h0; h < h0 + H_DIM / 4; ++h)
    sum = fmaf(xs[h], wr[h * E_NUM + e], sum);
  part[q][e] = sum;
  __syncthreads();

  if (tid < 64) {  // wave 0, lane == expert
    float logit = part[0][e] + part[1][e] + part[2][e] + part[3][e];
    out_logits[t * E_NUM + e] = logit;

    // softmax over 64 lanes
    float m = logit;
    #pragma unroll
    for (int off = 32; off; off >>= 1) m = fmaxf(m, __shfl_xor(m, off));
    float p = __expf(logit - m);
    float s = p;
    #pragma unroll
    for (int off = 32; off; off >>= 1) s += __shfl_xor(s, off);
    float my = p / s;  // prob

    // top-8: iterative argmax with low-index tie-break (matches lax.top_k)
    int sel_i = 0; float sel_v = 0.f;
    for (int k = 0; k < K_TOP; ++k) {
      float v = my; int i = e;
      #pragma unroll
      for (int off = 32; off; off >>= 1) {
        float ov = __shfl_xor(v, off); int oi = __shfl_xor(i, off);
        if (ov > v || (ov == v && oi < i)) { v = ov; i = oi; }
      }
      if (e == i) my = -1.f;          // remove winner
      if (e == k) { sel_v = v; sel_i = i; }
    }
    float s8 = (e < K_TOP) ? sel_v : 0.f;
    #pragma unroll
    for (int off = 32; off; off >>= 1) s8 += __shfl_xor(s8, off);
    s8 = fmaxf(s8, 1e-9f);
    if (e < K_TOP) {
      topk_idx[t * K_TOP + e] = sel_i;
      topk_w[t * K_TOP + e]   = sel_v / s8;   // normalized top-k weight
    }
  }
}

// ---------------- grouping: histogram / scan / scatter ----------------
__global__ void histo_kernel(const int* __restrict__ topk_idx, int* counts) {
  int i = blockIdx.x * 256 + threadIdx.x;
  atomicAdd(&counts[topk_idx[i]], 1);
}

__global__ void scan_kernel(const int* __restrict__ counts, int* offsets) {
  if (threadIdx.x == 0) {
    int r = 0;
    for (int e = 0; e < E_NUM; ++e) { offsets[e] = r; r += counts[e]; }
  }
}

__global__ void scatter_kernel(const int* __restrict__ topk_idx,
                               const float* __restrict__ topk_w,
                               const int* __restrict__ offsets, int* cursor,
                               int* __restrict__ perm_token,
                               float* __restrict__ perm_w) {
  int i = blockIdx.x * 256 + threadIdx.x;
  int e = topk_idx[i];
  int p = atomicAdd(&cursor[e], 1);
  int pos = offsets[e] + p;
  perm_token[pos] = i >> 3;   // token id
  perm_w[pos]     = topk_w[i];
}

// ---------------- fused expert FFN ----------------
// grid: (tiles=128, experts=64); block 256 threads.
// Per block: TT=16 tokens of expert e.
//   phase1: h = silu(X@wg) * (X@wu)  -> hbuf[16][768] in LDS
//   phase2: out += (h @ wd) * w      -> fp32 atomicAdd
__global__ __launch_bounds__(256) void expert_kernel(
    const float* __restrict__ x, const float* __restrict__ wg,
    const float* __restrict__ wu, const float* __restrict__ wd,
    const int* __restrict__ counts, const int* __restrict__ offsets,
    const int* __restrict__ perm_token, const float* __restrict__ perm_w,
    float* __restrict__ out) {
  const int e = blockIdx.y;
  const int n = counts[e];
  const int t0 = blockIdx.x * TT;
  if (t0 >= n) return;
  const int tid = threadIdx.x;

  __shared__ __align__(16) float xs[TT][HC];
  __shared__ __align__(16) float hbuf[TT][I_DIM];
  __shared__ int tok_s[TT];
  __shared__ float w_s[TT];

  const int base = offsets[e];
  if (tid < TT) {
    int idx = t0 + tid;
    if (idx < n) { tok_s[tid] = perm_token[base + idx]; w_s[tid] = perm_w[base + idx]; }
    else         { tok_s[tid] = 0;                      w_s[tid] = 0.f; }
  }

  const float* wg_e = wg + (size_t)e * H_DIM * I_DIM;
  const float* wu_e = wu + (size_t)e * H_DIM * I_DIM;

  // ---- phase 1: gate/up GEMMs, I in chunks of 256 (thread owns column c) ----
  for (int ic = 0; ic < I_DIM; ic += 256) {
    const int c = ic + tid;
    float accg[TT], accu[TT];
    #pragma unroll
    for (int t = 0; t < TT; ++t) { accg[t] = 0.f; accu[t] = 0.f; }

    for (int hb = 0; hb < H_DIM; hb += HC) {
      __syncthreads();  // previous xs consumers done (also covers tok_s on first pass)
      {  // stage X chunk [16][128]: 512 float4, 2 per thread
        int r = tid >> 5, l = tid & 31;
        #pragma unroll
        for (int pass = 0; pass < 2; ++pass) {
          int rr = r + pass * 8;
          const float4* src = (const float4*)(x + (size_t)tok_s[rr] * H_DIM + hb);
          ((float4*)&xs[rr][0])[l] = src[l];
        }
      }
      __syncthreads();

      #pragma unroll 1
      for (int h4 = 0; h4 < HC; h4 += 4) {
        float wgv[4], wuv[4];
        #pragma unroll
        for (int j = 0; j < 4; ++j) {
          wgv[j] = wg_e[(size_t)(hb + h4 + j) * I_DIM + c];
          wuv[j] = wu_e[(size_t)(hb + h4 + j) * I_DIM + c];
        }
        #pragma unroll
        for (int t = 0; t < TT; ++t) {
          float4 xv = *(const float4*)&xs[t][h4];  // LDS broadcast
          accg[t] = fmaf(xv.x, wgv[0], accg[t]);
          accg[t] = fmaf(xv.y, wgv[1], accg[t]);
          accg[t] = fmaf(xv.z, wgv[2], accg[t]);
          accg[t] = fmaf(xv.w, wgv[3], accg[t]);
          accu[t] = fmaf(xv.x, wuv[0], accu[t]);
          accu[t] = fmaf(xv.y, wuv[1], accu[t]);
          accu[t] = fmaf(xv.z, wuv[2], accu[t]);
          accu[t] = fmaf(xv.w, wuv[3], accu[t]);
        }
      }
    }
    #pragma unroll
    for (int t = 0; t < TT; ++t) {
      float g = accg[t];
      float sig = 1.f / (1.f + __expf(-g));
      hbuf[t][c] = g * sig * accu[t];   // silu(gate) * up
    }
  }
  __syncthreads();

  // ---- phase 2: down GEMM, thread owns 2 output columns ----
  const float* wd_e = wd + (size_t)e * I_DIM * H_DIM;
  for (int oc = 0; oc < H_DIM; oc += 512) {
    float acc0[TT], acc1[TT];
    #pragma unroll
    for (int t = 0; t < TT; ++t) { acc0[t] = 0.f; acc1[t] = 0.f; }

    #pragma unroll 1
    for (int i4 = 0; i4 < I_DIM; i4 += 4) {
      float wdv0[4], wdv1[4];
      #pragma unroll
      for (int j = 0; j < 4; ++j) {
        wdv0[j] = wd_e[(size_t)(i4 + j) * H_DIM + oc + tid];
        wdv1[j] = wd_e[(size_t)(i4 + j) * H_DIM + oc + 256 + tid];
      }
      #pragma unroll
      for (int t = 0; t < TT; ++t) {
        float4 hv = *(const float4*)&hbuf[t][i4];  // LDS broadcast
        acc0[t] = fmaf(hv.x, wdv0[0], acc0[t]);
        acc0[t] = fmaf(hv.y, wdv0[1], acc0[t]);
        acc0[t] = fmaf(hv.z, wdv0[2], acc0[t]);
        acc0[t] = fmaf(hv.w, wdv0[3], acc0[t]);
        acc1[t] = fmaf(hv.x, wdv1[0], acc1[t]);
        acc1[t] = fmaf(hv.y, wdv1[1], acc1[t]);
        acc1[t] = fmaf(hv.z, wdv1[2], acc1[t]);
        acc1[t] = fmaf(hv.w, wdv1[3], acc1[t]);
      }
    }
    #pragma unroll
    for (int t = 0; t < TT; ++t) {
      float wt = w_s[t];            // uniform across threads
      if (wt != 0.f) {
        atomicAdd(&out[(size_t)tok_s[t] * H_DIM + oc + tid],       acc0[t] * wt);
        atomicAdd(&out[(size_t)tok_s[t] * H_DIM + oc + 256 + tid], acc1[t] * wt);
      }
    }
  }
}

// ---------------- launch ----------------
extern "C" void kernel_launch(void* const* d_in, const int* in_sizes, int n_in,
                              void* d_out, int out_size, void* d_ws, size_t ws_size,
                              hipStream_t stream) {
  const float* x   = (const float*)d_in[0];  // [T, H]
  const float* wr  = (const float*)d_in[1];  // [H, E]
  const float* wg  = (const float*)d_in[2];  // [E, H, I]
  const float* wu  = (const float*)d_in[3];  // [E, H, I]
  const float* wd  = (const float*)d_in[4];  // [E, I, H]

  float* out_final  = (float*)d_out;                          // [T, H]
  float* out_logits = (float*)d_out + (size_t)T_TOK * H_DIM;  // [T, E]

  char* ws = (char*)d_ws;
  int*   topk_idx  = (int*)  (ws + WS_TOPK_IDX);
  float* topk_w    = (float*)(ws + WS_TOPK_W);
  int*   counts    = (int*)  (ws + WS_COUNTS);
  int*   offsets   = (int*)  (ws + WS_OFFSETS);
  int*   cursor    = (int*)  (ws + WS_CURSOR);
  int*   perm_tok  = (int*)  (ws + WS_PERM_TOK);
  float* perm_w    = (float*)(ws + WS_PERM_W);

  // zero the accumulated output region and the counters (ws is poisoned 0xAA)
  hipMemsetAsync(out_final, 0, (size_t)T_TOK * H_DIM * sizeof(float), stream);
  hipMemsetAsync(ws + WS_COUNTS, 0, 3 * E_NUM * sizeof(int), stream);

  router_kernel<<<T_TOK, 256, 0, stream>>>(x, wr, out_logits, topk_idx, topk_w);
  histo_kernel<<<T_TOK * K_TOP / 256, 256, 0, stream>>>(topk_idx, counts);
  scan_kernel<<<1, 64, 0, stream>>>(counts, offsets);
  scatter_kernel<<<T_TOK * K_TOP / 256, 256, 0, stream>>>(
      topk_idx, topk_w, offsets, cursor, perm_tok, perm_w);

  dim3 egrid(T_TOK / TT, E_NUM);  // 128 tiles x 64 experts; inactive tiles exit
  expert_kernel<<<egrid, 256, 0, stream>>>(
      x, wg, wu, wd, counts, offsets, perm_tok, perm_w, out_final);
}